// Round 2
// baseline (1453.485 us; speedup 1.0000x reference)
//
#include <hip/hip_runtime.h>

#define NN 50000
#define EE 800000

// ---------- helpers ----------
__device__ __forceinline__ float bf_lo(unsigned u){ return __uint_as_float(u << 16); }
__device__ __forceinline__ float bf_hi(unsigned u){ return __uint_as_float(u & 0xffff0000u); }
__device__ __forceinline__ float bf2f(unsigned short u){ return __uint_as_float(((unsigned)u) << 16); }
__device__ __forceinline__ unsigned short f2bf(float f){
  unsigned x = __float_as_uint(f);
  x += 0x7fffu + ((x >> 16) & 1u);       // RNE
  return (unsigned short)(x >> 16);
}
__device__ __forceinline__ float gelu_exact(float x){
  return x * 0.5f * (1.0f + erff(x * 0.70710678118654752f));
}
__device__ __forceinline__ float rcp_fast(float x){ return __builtin_amdgcn_rcpf(x); }
// tanh-form gelu: 0.5x(1+tanh(0.79788456(x+0.044715x^3))) = x - x*sigmoid(-2y)
__device__ __forceinline__ float gelu_fast(float x){
  float x2 = x * x;
  float y  = x * fmaf(x2, 0.0356774081f, 0.7978845608f);
  float e  = __expf(y + y);
  return x - x * rcp_fast(e + 1.0f);
}
__device__ __forceinline__ float tanh_fast(float x){
  float e = __expf(x + x);
  return 1.0f - 2.0f * rcp_fast(e + 1.0f);
}
__device__ __forceinline__ void atomic_add_f32(float* p, float v){
  __hip_atomic_fetch_add(p, v, __ATOMIC_RELAXED, __HIP_MEMORY_SCOPE_AGENT);
}

// ---------- kernel 1: LN + QKV (bf16 out) + seq-normalize (bf16 out) ----------
#define NB 48
__global__ __launch_bounds__(384) void node_pre(
    const float* __restrict__ x, const float* __restrict__ seq,
    const float* __restrict__ ln_g, const float* __restrict__ ln_b,
    const float* __restrict__ Wq, const float* __restrict__ bq,
    const float* __restrict__ Wk, const float* __restrict__ bk,
    const float* __restrict__ Wv, const float* __restrict__ bv,
    unsigned short* __restrict__ qb, unsigned short* __restrict__ kb,
    unsigned short* __restrict__ vb, unsigned short* __restrict__ snb)
{
  __shared__ float h_lds[NB][132];
  const int t = threadIdx.x;
  const int nbase = blockIdx.x * NB;

  {
    const int row = t >> 3, sub = t & 7;
    const int n = nbase + row;
    if (n < NN) {
      const float* xp = x + (size_t)n * 128 + sub * 16;
      float vals[16];
      float s = 0.f, ss = 0.f;
      #pragma unroll
      for (int j = 0; j < 16; j += 4) {
        float4 v4 = *(const float4*)(xp + j);
        vals[j] = v4.x; vals[j+1] = v4.y; vals[j+2] = v4.z; vals[j+3] = v4.w;
        s += v4.x + v4.y + v4.z + v4.w;
        ss += v4.x*v4.x + v4.y*v4.y + v4.z*v4.z + v4.w*v4.w;
      }
      #pragma unroll
      for (int o = 1; o < 8; o <<= 1) { s += __shfl_xor(s, o); ss += __shfl_xor(ss, o); }
      float mu = s * (1.f / 128.f);
      float var = ss * (1.f / 128.f) - mu * mu;
      float rs = rsqrtf(var + 1e-5f);
      #pragma unroll
      for (int j = 0; j < 16; j++) {
        int c = sub * 16 + j;
        h_lds[row][c] = (vals[j] - mu) * rs * ln_g[c] + ln_b[c];
      }
      const float* sp = seq + (size_t)n * 64 + sub * 8;
      float4 a = *(const float4*)(sp);
      float4 b4 = *(const float4*)(sp + 4);
      float q2 = a.x*a.x + a.y*a.y + a.z*a.z + a.w*a.w
               + b4.x*b4.x + b4.y*b4.y + b4.z*b4.z + b4.w*b4.w;
      #pragma unroll
      for (int o = 1; o < 8; o <<= 1) q2 += __shfl_xor(q2, o);
      float inv = 1.0f / fmaxf(sqrtf(q2), 1e-12f);
      unsigned short* op = snb + (size_t)n * 64 + sub * 8;
      op[0]=f2bf(a.x*inv);  op[1]=f2bf(a.y*inv);  op[2]=f2bf(a.z*inv);  op[3]=f2bf(a.w*inv);
      op[4]=f2bf(b4.x*inv); op[5]=f2bf(b4.y*inv); op[6]=f2bf(b4.z*inv); op[7]=f2bf(b4.w*inv);
    }
  }
  __syncthreads();

  const int mat = t >> 7;
  const int r = t & 127;
  const float* W = (mat == 0) ? Wq : (mat == 1) ? Wk : Wv;
  const float* B = (mat == 0) ? bq : (mat == 1) ? bk : bv;
  unsigned short* O = (mat == 0) ? qb : (mat == 1) ? kb : vb;

  float acc[NB];
  #pragma unroll
  for (int n = 0; n < NB; n++) acc[n] = 0.f;

  for (int i = 0; i < 128; i += 4) {
    float4 w4 = *(const float4*)(W + (size_t)r * 128 + i);
    #pragma unroll
    for (int n = 0; n < NB; n++) {
      float4 h4 = *(const float4*)(&h_lds[n][i]);
      acc[n] += w4.x*h4.x + w4.y*h4.y + w4.z*h4.z + w4.w*h4.w;
    }
  }
  float bias = B[r];
  #pragma unroll
  for (int n = 0; n < NB; n++) {
    int ng = nbase + n;
    if (ng < NN) O[(size_t)ng * 128 + r] = f2bf(acc[n] + bias);
  }
}

// ---------- kernel 2a: per-edge logits -> exp (bf16) + denominator atomics ----------
__global__ __launch_bounds__(256, 5) void edge_logits(
    const int* __restrict__ ei, const float* __restrict__ edge_attr,
    const unsigned short* __restrict__ qb, const unsigned short* __restrict__ kb,
    const unsigned short* __restrict__ snb,
    const float* __restrict__ We0a, const float* __restrict__ be0a,
    const float* __restrict__ We0b, const float* __restrict__ be0b,
    const float* __restrict__ We1a, const float* __restrict__ be1a,
    const float* __restrict__ We1b, const float* __restrict__ be1b,
    const float* __restrict__ Ws1, const float* __restrict__ bs1,
    const float* __restrict__ Ws2, const float* __restrict__ bs2,
    float* __restrict__ den, unsigned short* __restrict__ exwb)
{
  __shared__ unsigned short sWs1[128 * 64];   // bf16 weights, [j][i]
  __shared__ float sWs2T[128 * 8];            // [j][o]
  __shared__ float sWea[2 * 32 * 16];
  __shared__ float sWebT[2 * 32 * 8];
  __shared__ float sbea[2 * 32];
  __shared__ float sbeb[2 * 8];
  __shared__ float sbs1[128];
  __shared__ float sbs2[8];

  const int t = threadIdx.x;
  for (int idx = t; idx < 8192; idx += 256) sWs1[idx] = f2bf(Ws1[idx]);
  for (int idx = t; idx < 1024; idx += 256) { int j = idx >> 3, o = idx & 7; sWs2T[idx] = Ws2[o * 128 + j]; }
  for (int idx = t; idx < 1024; idx += 256) sWea[idx] = (idx < 512) ? We0a[idx] : We1a[idx - 512];
  for (int idx = t; idx < 512;  idx += 256) { int e2 = idx >> 8, rem = idx & 255, j = rem >> 3, o = rem & 7;
                                              sWebT[idx] = (e2 ? We1b : We0b)[o * 32 + j]; }
  if (t < 64)  sbea[t] = (t < 32) ? be0a[t] : be1a[t - 32];
  if (t < 16)  sbeb[t] = (t < 8) ? be0b[t] : be1b[t - 8];
  if (t < 128) sbs1[t] = bs1[t];
  if (t < 8)   sbs2[t] = bs2[t];
  __syncthreads();

  const int e = blockIdx.x * 256 + t;
  const int src = ei[e];
  const int dst = ei[EE + e];

  // ---- edge-type MLP ----
  float ef[16], a16, a17;
  {
    const float2* p2 = (const float2*)(edge_attr + (size_t)e * 18);
    float2 p[9];
    #pragma unroll
    for (int i = 0; i < 9; i++) p[i] = p2[i];
    #pragma unroll
    for (int i = 0; i < 8; i++) { ef[2*i] = p[i].x; ef[2*i+1] = p[i].y; }
    a16 = p[8].x; a17 = p[8].y;
  }
  const int sel = (a17 > a16) ? 1 : 0;
  const float* Wa = sWea + sel * 512;
  const float* Wb = sWebT + sel * 256;
  const float* ba = sbea + sel * 32;
  const float* bb = sbeb + sel * 8;
  float m[8];
  #pragma unroll
  for (int o = 0; o < 8; o++) m[o] = bb[o];
  for (int j = 0; j < 32; j++) {
    float hs = ba[j];
    #pragma unroll
    for (int i = 0; i < 16; i++) hs += Wa[j * 16 + i] * ef[i];
    hs = fmaxf(hs, 0.f);
    #pragma unroll
    for (int o = 0; o < 8; o++) m[o] += Wb[j * 8 + o] * hs;
  }

  // ---- seq MLP: sd = sn[dst]-sn[src] ----
  float sd[64];
  {
    const unsigned short* sA = snb + (size_t)dst * 64;
    const unsigned short* sB = snb + (size_t)src * 64;
    #pragma unroll
    for (int i8 = 0; i8 < 64; i8 += 8) {
      uint4 ua = *(const uint4*)(sA + i8);
      uint4 ub = *(const uint4*)(sB + i8);
      unsigned au[4] = {ua.x, ua.y, ua.z, ua.w};
      unsigned bu[4] = {ub.x, ub.y, ub.z, ub.w};
      #pragma unroll
      for (int w = 0; w < 4; w++) {
        sd[i8 + 2*w]     = bf_lo(au[w]) - bf_lo(bu[w]);
        sd[i8 + 2*w + 1] = bf_hi(au[w]) - bf_hi(bu[w]);
      }
    }
  }
  float sb[8];
  #pragma unroll
  for (int o = 0; o < 8; o++) sb[o] = sbs2[o];
  for (int j = 0; j < 128; j++) {
    float acc = sbs1[j];
    const uint4* wp = (const uint4*)(sWs1 + j * 64);
    #pragma unroll
    for (int u = 0; u < 8; u++) {
      uint4 w = wp[u];                      // 8 bf16 weights, broadcast read
      unsigned wa[4] = {w.x, w.y, w.z, w.w};
      #pragma unroll
      for (int p = 0; p < 4; p++) {
        int i = u * 8 + p * 2;
        acc += bf_lo(wa[p]) * sd[i] + bf_hi(wa[p]) * sd[i + 1];
      }
    }
    float g = gelu_fast(acc);
    float4 w2a = *(const float4*)(&sWs2T[j * 8]);
    float4 w2b = *(const float4*)(&sWs2T[j * 8 + 4]);
    sb[0] += w2a.x * g; sb[1] += w2a.y * g; sb[2] += w2a.z * g; sb[3] += w2a.w * g;
    sb[4] += w2b.x * g; sb[5] += w2b.y * g; sb[6] += w2b.z * g; sb[7] += w2b.w * g;
  }

  // ---- QK dots + exp + den atomics + exw store ----
  {
    const unsigned short* qrow = qb + (size_t)dst * 128;
    const unsigned short* krow = kb + (size_t)src * 128;
    unsigned pk[4];
    #pragma unroll
    for (int h = 0; h < 8; h++) {
      const uint4* qp = (const uint4*)(qrow + h * 16);
      const uint4* kp = (const uint4*)(krow + h * 16);
      float dot = 0.f;
      #pragma unroll
      for (int u = 0; u < 2; u++) {
        uint4 qu = qp[u], ku = kp[u];
        unsigned qa[4] = {qu.x, qu.y, qu.z, qu.w};
        unsigned ka[4] = {ku.x, ku.y, ku.z, ku.w};
        #pragma unroll
        for (int w = 0; w < 4; w++)
          dot += bf_lo(qa[w]) * bf_lo(ka[w]) + bf_hi(qa[w]) * bf_hi(ka[w]);
      }
      float logit = dot * 0.25f + m[h] + 0.1f * tanh_fast(sb[h]);
      float ex = __expf(logit);
      atomic_add_f32(&den[(size_t)dst * 8 + h], ex);
      unsigned short exu = f2bf(ex);
      if (h & 1) pk[h >> 1] |= ((unsigned)exu) << 16;
      else       pk[h >> 1]  = (unsigned)exu;
    }
    uint4 st; st.x = pk[0]; st.y = pk[1]; st.z = pk[2]; st.w = pk[3];
    *(uint4*)(exwb + (size_t)e * 8) = st;
  }
}

// ---------- kernel 2b: message scatter (no LDS, high occupancy) ----------
__global__ __launch_bounds__(256) void scatter_k(
    const int* __restrict__ ei, const unsigned short* __restrict__ vb,
    const unsigned short* __restrict__ exwb, float* __restrict__ num)
{
  const int t = threadIdx.x, lane = t & 63;
  const int ebase = blockIdx.x * 256 + (t >> 6) * 64;
  const int e = ebase + lane;
  const int src = ei[e];
  const int dst = ei[EE + e];
  const int h = lane >> 3;
  const int c0 = lane * 2;

  #pragma unroll 4
  for (int el = 0; el < 64; el++) {
    int s2 = __shfl(src, el);
    int d2 = __shfl(dst, el);
    float ex = bf2f(exwb[(size_t)(ebase + el) * 8 + h]);
    unsigned vv = *(const unsigned*)(vb + (size_t)s2 * 128 + c0);
    atomic_add_f32(&num[(size_t)d2 * 128 + c0],     bf_lo(vv) * ex);
    atomic_add_f32(&num[(size_t)d2 * 128 + c0 + 1], bf_hi(vv) * ex);
  }
}

// ---------- kernel 3: out = gelu(num/(den+1e-12)) + x ----------
__global__ __launch_bounds__(256) void finalize_k(
    const float* __restrict__ x, const float* __restrict__ num,
    const float* __restrict__ den, float* __restrict__ out)
{
  int idx = blockIdx.x * 256 + threadIdx.x;
  int n = idx >> 5;
  int c4 = (idx & 31) * 4;
  int h = c4 >> 4;
  float dv = den[(size_t)n * 8 + h] + 1e-12f;
  float inv = 1.0f / dv;
  float4 nm = *(const float4*)(num + (size_t)n * 128 + c4);
  float4 xx = *(const float4*)(x + (size_t)n * 128 + c4);
  float4 o;
  o.x = gelu_exact(nm.x * inv) + xx.x;
  o.y = gelu_exact(nm.y * inv) + xx.y;
  o.z = gelu_exact(nm.z * inv) + xx.z;
  o.w = gelu_exact(nm.w * inv) + xx.w;
  *(float4*)(out + (size_t)n * 128 + c4) = o;
}

extern "C" void kernel_launch(void* const* d_in, const int* in_sizes, int n_in,
                              void* d_out, int out_size, void* d_ws, size_t ws_size,
                              hipStream_t stream)
{
  const float* x    = (const float*)d_in[0];
  const int*   ei   = (const int*)d_in[1];
  const float* ea   = (const float*)d_in[2];
  const float* seq  = (const float*)d_in[3];
  const float* ln_g = (const float*)d_in[4];
  const float* ln_b = (const float*)d_in[5];
  const float* Wq   = (const float*)d_in[6];
  const float* bq   = (const float*)d_in[7];
  const float* Wk   = (const float*)d_in[8];
  const float* bk   = (const float*)d_in[9];
  const float* Wv   = (const float*)d_in[10];
  const float* bv   = (const float*)d_in[11];
  const float* We0a = (const float*)d_in[12];
  const float* be0a = (const float*)d_in[13];
  const float* We0b = (const float*)d_in[14];
  const float* be0b = (const float*)d_in[15];
  const float* We1a = (const float*)d_in[16];
  const float* be1a = (const float*)d_in[17];
  const float* We1b = (const float*)d_in[18];
  const float* be1b = (const float*)d_in[19];
  const float* Ws1  = (const float*)d_in[20];
  const float* bs1  = (const float*)d_in[21];
  const float* Ws2  = (const float*)d_in[22];
  const float* bs2  = (const float*)d_in[23];
  float* out = (float*)d_out;

  // workspace layout (~85 MB)
  unsigned short* qb  = (unsigned short*)d_ws;
  unsigned short* kb  = qb + (size_t)NN * 128;
  unsigned short* vb  = kb + (size_t)NN * 128;
  unsigned short* snb = vb + (size_t)NN * 128;
  float* num = (float*)(snb + (size_t)NN * 64);
  float* den = num + (size_t)NN * 128;
  unsigned short* exwb = (unsigned short*)(den + (size_t)NN * 8);

  hipMemsetAsync(num, 0, (size_t)(NN * 128 + NN * 8) * sizeof(float), stream);

  node_pre<<<(NN + NB - 1) / NB, 384, 0, stream>>>(
      x, seq, ln_g, ln_b, Wq, bq, Wk, bk, Wv, bv, qb, kb, vb, snb);

  edge_logits<<<EE / 256, 256, 0, stream>>>(
      ei, ea, qb, kb, snb,
      We0a, be0a, We0b, be0b, We1a, be1a, We1b, be1b,
      Ws1, bs1, Ws2, bs2, den, exwb);

  scatter_k<<<EE / 256, 256, 0, stream>>>(ei, vb, exwb, num);

  finalize_k<<<(NN * 32) / 256, 256, 0, stream>>>(x, num, den, out);
}

// Round 3
// 768.240 us; speedup vs baseline: 1.8920x; 1.8920x over previous
//
#include <hip/hip_runtime.h>
#include <hip/hip_fp16.h>

#define NN 50000
#define EE 800000

typedef unsigned int u32;
typedef unsigned short u16;

// ---------- helpers ----------
__device__ __forceinline__ float bf_lo(u32 u){ return __uint_as_float(u << 16); }
__device__ __forceinline__ float bf_hi(u32 u){ return __uint_as_float(u & 0xffff0000u); }
__device__ __forceinline__ u16 f2bf(float f){
  u32 x = __float_as_uint(f);
  x += 0x7fffu + ((x >> 16) & 1u);       // RNE
  return (u16)(x >> 16);
}
__device__ __forceinline__ float gelu_exact(float x){
  return x * 0.5f * (1.0f + erff(x * 0.70710678118654752f));
}
__device__ __forceinline__ float rcp_fast(float x){ return __builtin_amdgcn_rcpf(x); }
__device__ __forceinline__ float gelu_fast(float x){
  float x2 = x * x;
  float y  = x * fmaf(x2, 0.0356774081f, 0.7978845608f);
  float e  = __expf(y + y);
  return x - x * rcp_fast(e + 1.0f);
}
__device__ __forceinline__ float tanh_fast(float x){
  float e = __expf(x + x);
  return 1.0f - 2.0f * rcp_fast(e + 1.0f);
}
__device__ __forceinline__ void atomic_add_f32(float* p, float v){
  __hip_atomic_fetch_add(p, v, __ATOMIC_RELAXED, __HIP_MEMORY_SCOPE_AGENT);
}
__device__ __forceinline__ __half2 as_h2(u32 u){ return __builtin_bit_cast(__half2, u); }

// ---------- kernel 0: weight prep (f16 Ws1, transposed Ws2) ----------
__global__ __launch_bounds__(256) void prep_w(
    const float* __restrict__ Ws1, const float* __restrict__ Ws2,
    __half* __restrict__ Ws1h, float* __restrict__ Ws2t)
{
  int i = blockIdx.x * 256 + threadIdx.x;
  if (i < 8192) {
    Ws1h[i] = __float2half(Ws1[i]);
  } else if (i < 8192 + 1024) {
    int k = i - 8192;
    int j = k >> 3, o = k & 7;
    Ws2t[k] = Ws2[o * 128 + j];
  }
}

// ---------- kernel 1: LN + QKV (q,k f16; v bf16) + seq-normalize (f16) ----------
#define NB 48
__global__ __launch_bounds__(384) void node_pre(
    const float* __restrict__ x, const float* __restrict__ seq,
    const float* __restrict__ ln_g, const float* __restrict__ ln_b,
    const float* __restrict__ Wq, const float* __restrict__ bq,
    const float* __restrict__ Wk, const float* __restrict__ bk,
    const float* __restrict__ Wv, const float* __restrict__ bv,
    __half* __restrict__ qb, __half* __restrict__ kb,
    u16* __restrict__ vb, __half* __restrict__ snb)
{
  __shared__ float h_lds[NB][132];
  const int t = threadIdx.x;
  const int nbase = blockIdx.x * NB;

  {
    const int row = t >> 3, sub = t & 7;
    const int n = nbase + row;
    if (n < NN) {
      const float* xp = x + (size_t)n * 128 + sub * 16;
      float vals[16];
      float s = 0.f, ss = 0.f;
      #pragma unroll
      for (int j = 0; j < 16; j += 4) {
        float4 v4 = *(const float4*)(xp + j);
        vals[j] = v4.x; vals[j+1] = v4.y; vals[j+2] = v4.z; vals[j+3] = v4.w;
        s += v4.x + v4.y + v4.z + v4.w;
        ss += v4.x*v4.x + v4.y*v4.y + v4.z*v4.z + v4.w*v4.w;
      }
      #pragma unroll
      for (int o = 1; o < 8; o <<= 1) { s += __shfl_xor(s, o); ss += __shfl_xor(ss, o); }
      float mu = s * (1.f / 128.f);
      float var = ss * (1.f / 128.f) - mu * mu;
      float rs = rsqrtf(var + 1e-5f);
      #pragma unroll
      for (int j = 0; j < 16; j++) {
        int c = sub * 16 + j;
        h_lds[row][c] = (vals[j] - mu) * rs * ln_g[c] + ln_b[c];
      }
      const float* sp = seq + (size_t)n * 64 + sub * 8;
      float4 a = *(const float4*)(sp);
      float4 b4 = *(const float4*)(sp + 4);
      float q2 = a.x*a.x + a.y*a.y + a.z*a.z + a.w*a.w
               + b4.x*b4.x + b4.y*b4.y + b4.z*b4.z + b4.w*b4.w;
      #pragma unroll
      for (int o = 1; o < 8; o <<= 1) q2 += __shfl_xor(q2, o);
      float inv = 1.0f / fmaxf(sqrtf(q2), 1e-12f);
      __half* op = snb + (size_t)n * 64 + sub * 8;
      op[0]=__float2half(a.x*inv);  op[1]=__float2half(a.y*inv);
      op[2]=__float2half(a.z*inv);  op[3]=__float2half(a.w*inv);
      op[4]=__float2half(b4.x*inv); op[5]=__float2half(b4.y*inv);
      op[6]=__float2half(b4.z*inv); op[7]=__float2half(b4.w*inv);
    }
  }
  __syncthreads();

  const int mat = t >> 7;
  const int r = t & 127;
  const float* W = (mat == 0) ? Wq : (mat == 1) ? Wk : Wv;
  const float* B = (mat == 0) ? bq : (mat == 1) ? bk : bv;

  float acc[NB];
  #pragma unroll
  for (int n = 0; n < NB; n++) acc[n] = 0.f;

  for (int i = 0; i < 128; i += 4) {
    float4 w4 = *(const float4*)(W + (size_t)r * 128 + i);
    #pragma unroll
    for (int n = 0; n < NB; n++) {
      float4 h4 = *(const float4*)(&h_lds[n][i]);
      acc[n] += w4.x*h4.x + w4.y*h4.y + w4.z*h4.z + w4.w*h4.w;
    }
  }
  float bias = B[r];
  __half* Oh = (mat == 0) ? qb : kb;
  #pragma unroll
  for (int n = 0; n < NB; n++) {
    int ng = nbase + n;
    if (ng < NN) {
      float val = acc[n] + bias;
      if (mat == 2) vb[(size_t)ng * 128 + r] = f2bf(val);
      else          Oh[(size_t)ng * 128 + r] = __float2half(val);
    }
  }
}

// ---------- kernel 2: fused edge logits + softmax-numerator scatter ----------
__global__ __launch_bounds__(256, 4) void edge_fused(
    const int* __restrict__ ei, const float* __restrict__ edge_attr,
    const __half* __restrict__ qb, const __half* __restrict__ kb,
    const u16* __restrict__ vb, const __half* __restrict__ snb,
    const float* __restrict__ We0a, const float* __restrict__ be0a,
    const float* __restrict__ We0b, const float* __restrict__ be0b,
    const float* __restrict__ We1a, const float* __restrict__ be1a,
    const float* __restrict__ We1b, const float* __restrict__ be1b,
    const __half* __restrict__ Ws1h, const float* __restrict__ bs1,
    const float* __restrict__ Ws2t, const float* __restrict__ bs2,
    float* __restrict__ den, u16* __restrict__ numb)
{
  __shared__ float sWea[2 * 32 * 16];
  __shared__ float sWebT[2 * 32 * 8];
  __shared__ float sbea[2 * 32];
  __shared__ float sbeb[2 * 8];
  __shared__ float sEx[4 * 64 * 9];      // [wave][edge_lane][head], pad 9
  __shared__ u32 sSrcOff[4 * 64];
  __shared__ u32 sDstOff[4 * 64];

  const int t = threadIdx.x;
  for (int idx = t; idx < 1024; idx += 256) sWea[idx] = (idx < 512) ? We0a[idx] : We1a[idx - 512];
  for (int idx = t; idx < 512;  idx += 256) { int e2 = idx >> 8, rem = idx & 255, j = rem >> 3, o = rem & 7;
                                              sWebT[idx] = (e2 ? We1b : We0b)[o * 32 + j]; }
  if (t < 64)  sbea[t] = (t < 32) ? be0a[t] : be1a[t - 32];
  if (t < 16)  sbeb[t] = (t < 8) ? be0b[t] : be1b[t - 8];
  __syncthreads();

  const int e = blockIdx.x * 256 + t;
  const int lane = t & 63, wid = t >> 6;
  const int src = ei[e];
  const int dst = ei[EE + e];

  // stash byte offsets for the scatter phase (wave-private LDS, no barrier)
  sSrcOff[wid * 64 + lane] = (u32)src * 256u;   // vb row = 128 bf16 = 256 B
  sDstOff[wid * 64 + lane] = (u32)dst * 256u;   // numb row = 128 bf16 = 256 B

  // ---- edge-type MLP (f32, small) ----
  float ef[16], a16, a17;
  {
    const float2* p2 = (const float2*)(edge_attr + (size_t)e * 18);
    float2 p[9];
    #pragma unroll
    for (int i = 0; i < 9; i++) p[i] = p2[i];
    #pragma unroll
    for (int i = 0; i < 8; i++) { ef[2*i] = p[i].x; ef[2*i+1] = p[i].y; }
    a16 = p[8].x; a17 = p[8].y;
  }
  const int sel = (a17 > a16) ? 1 : 0;
  const float* Wa = sWea + sel * 512;
  const float* Wb = sWebT + sel * 256;
  const float* ba = sbea + sel * 32;
  const float* bb = sbeb + sel * 8;
  float m[8];
  #pragma unroll
  for (int o = 0; o < 8; o++) m[o] = bb[o];
  for (int j = 0; j < 32; j++) {
    float hs = ba[j];
    #pragma unroll
    for (int i = 0; i < 16; i++) hs += Wa[j * 16 + i] * ef[i];
    hs = fmaxf(hs, 0.f);
    #pragma unroll
    for (int o = 0; o < 8; o++) m[o] += Wb[j * 8 + o] * hs;
  }

  // ---- sd = sn[dst]-sn[src] in packed f16 ----
  __half2 sd2[32];
  {
    const uint4* sA = (const uint4*)(snb + (size_t)dst * 64);
    const uint4* sB = (const uint4*)(snb + (size_t)src * 64);
    #pragma unroll
    for (int u = 0; u < 8; u++) {
      uint4 ua = sA[u], ub = sB[u];
      sd2[u*4+0] = __hsub2(as_h2(ua.x), as_h2(ub.x));
      sd2[u*4+1] = __hsub2(as_h2(ua.y), as_h2(ub.y));
      sd2[u*4+2] = __hsub2(as_h2(ua.z), as_h2(ub.z));
      sd2[u*4+3] = __hsub2(as_h2(ua.w), as_h2(ub.w));
    }
  }

  // ---- seq MLP: weights via wave-uniform (scalar) loads ----
  float sb[8];
  #pragma unroll
  for (int o = 0; o < 8; o++) sb[o] = bs2[o];
  for (int j = 0; j < 128; j++) {
    const u32* wp = (const u32*)Ws1h + j * 32;   // uniform -> s_load
    __half2 a0 = __half2(__half(0.f), __half(0.f)), a1 = a0, a2 = a0, a3 = a0;
    #pragma unroll
    for (int u = 0; u < 32; u += 4) {
      a0 = __hfma2(as_h2(wp[u+0]), sd2[u+0], a0);
      a1 = __hfma2(as_h2(wp[u+1]), sd2[u+1], a1);
      a2 = __hfma2(as_h2(wp[u+2]), sd2[u+2], a2);
      a3 = __hfma2(as_h2(wp[u+3]), sd2[u+3], a3);
    }
    __half2 s01 = __hadd2(a0, a1), s23 = __hadd2(a2, a3);
    __half2 s = __hadd2(s01, s23);
    float accf = __half2float(__low2half(s)) + __half2float(__high2half(s)) + bs1[j];
    float g = gelu_fast(accf);
    float4 w2a = *(const float4*)(Ws2t + j * 8);       // uniform -> s_load
    float4 w2b = *(const float4*)(Ws2t + j * 8 + 4);
    sb[0] += w2a.x * g; sb[1] += w2a.y * g; sb[2] += w2a.z * g; sb[3] += w2a.w * g;
    sb[4] += w2b.x * g; sb[5] += w2b.y * g; sb[6] += w2b.z * g; sb[7] += w2b.w * g;
  }

  // ---- QK dots (f16) + exp + den atomics + sEx ----
  {
    const uint4* qp4 = (const uint4*)(qb + (size_t)dst * 128);
    const uint4* kp4 = (const uint4*)(kb + (size_t)src * 128);
    #pragma unroll
    for (int h = 0; h < 8; h++) {
      uint4 qa = qp4[2*h], qc = qp4[2*h+1];
      uint4 ka = kp4[2*h], kc = kp4[2*h+1];
      __half2 d2 = __half2(__half(0.f), __half(0.f));
      d2 = __hfma2(as_h2(qa.x), as_h2(ka.x), d2);
      d2 = __hfma2(as_h2(qa.y), as_h2(ka.y), d2);
      d2 = __hfma2(as_h2(qa.z), as_h2(ka.z), d2);
      d2 = __hfma2(as_h2(qa.w), as_h2(ka.w), d2);
      d2 = __hfma2(as_h2(qc.x), as_h2(kc.x), d2);
      d2 = __hfma2(as_h2(qc.y), as_h2(kc.y), d2);
      d2 = __hfma2(as_h2(qc.z), as_h2(kc.z), d2);
      d2 = __hfma2(as_h2(qc.w), as_h2(kc.w), d2);
      float dot = __half2float(__low2half(d2)) + __half2float(__high2half(d2));
      float logit = dot * 0.25f + m[h] + 0.1f * tanh_fast(sb[h]);
      float ex = __expf(logit);
      atomic_add_f32(&den[(size_t)dst * 8 + h], ex);
      sEx[wid * 576 + lane * 9 + h] = ex;
    }
  }

  // ---- scatter: wave-per-edge, pk_add_bf16 atomics ----
  {
    const int h = lane >> 3;
    const char* vbase = (const char*)vb + (size_t)(lane * 4);   // channel pair c0=2*lane
    char* nbase = (char*)numb + (size_t)(lane * 4);
    const int wb = wid * 64;
    for (int el = 0; el < 64; el++) {
      u32 so = sSrcOff[wb + el];            // broadcast reads
      u32 do_ = sDstOff[wb + el];
      float ex = sEx[wid * 576 + el * 9 + h];
      u32 vv = *(const u32*)(vbase + so);
      float p0 = bf_lo(vv) * ex;
      float p1 = bf_hi(vv) * ex;
      u32 pk_;
      asm("v_cvt_pk_bf16_f32 %0, %1, %2" : "=v"(pk_) : "v"(p0), "v"(p1));
      void* naddr = (void*)(nbase + (size_t)do_);
      asm volatile("global_atomic_pk_add_bf16 %0, %1, off" :: "v"(naddr), "v"(pk_) : "memory");
    }
  }
}

// ---------- kernel 3: out = gelu(num/(den+1e-12)) + x ----------
__global__ __launch_bounds__(256) void finalize_k(
    const float* __restrict__ x, const u16* __restrict__ numb,
    const float* __restrict__ den, float* __restrict__ out)
{
  int idx = blockIdx.x * 256 + threadIdx.x;   // NN*16 units of 8 channels
  int n = idx >> 4;
  int part = idx & 15;
  int c0 = part * 8;
  int h = part >> 1;
  float inv = 1.0f / (den[(size_t)n * 8 + h] + 1e-12f);
  uint4 nv = *(const uint4*)(numb + (size_t)n * 128 + c0);
  float4 xa = *(const float4*)(x + (size_t)n * 128 + c0);
  float4 xb = *(const float4*)(x + (size_t)n * 128 + c0 + 4);
  float4 oa, ob;
  oa.x = gelu_exact(bf_lo(nv.x) * inv) + xa.x;
  oa.y = gelu_exact(bf_hi(nv.x) * inv) + xa.y;
  oa.z = gelu_exact(bf_lo(nv.y) * inv) + xa.z;
  oa.w = gelu_exact(bf_hi(nv.y) * inv) + xa.w;
  ob.x = gelu_exact(bf_lo(nv.z) * inv) + xb.x;
  ob.y = gelu_exact(bf_hi(nv.z) * inv) + xb.y;
  ob.z = gelu_exact(bf_lo(nv.w) * inv) + xb.z;
  ob.w = gelu_exact(bf_hi(nv.w) * inv) + xb.w;
  *(float4*)(out + (size_t)n * 128 + c0) = oa;
  *(float4*)(out + (size_t)n * 128 + c0 + 4) = ob;
}

extern "C" void kernel_launch(void* const* d_in, const int* in_sizes, int n_in,
                              void* d_out, int out_size, void* d_ws, size_t ws_size,
                              hipStream_t stream)
{
  const float* x    = (const float*)d_in[0];
  const int*   ei   = (const int*)d_in[1];
  const float* ea   = (const float*)d_in[2];
  const float* seq  = (const float*)d_in[3];
  const float* ln_g = (const float*)d_in[4];
  const float* ln_b = (const float*)d_in[5];
  const float* Wq   = (const float*)d_in[6];
  const float* bq   = (const float*)d_in[7];
  const float* Wk   = (const float*)d_in[8];
  const float* bk   = (const float*)d_in[9];
  const float* Wv   = (const float*)d_in[10];
  const float* bv   = (const float*)d_in[11];
  const float* We0a = (const float*)d_in[12];
  const float* be0a = (const float*)d_in[13];
  const float* We0b = (const float*)d_in[14];
  const float* be0b = (const float*)d_in[15];
  const float* We1a = (const float*)d_in[16];
  const float* be1a = (const float*)d_in[17];
  const float* We1b = (const float*)d_in[18];
  const float* be1b = (const float*)d_in[19];
  const float* Ws1  = (const float*)d_in[20];
  const float* bs1  = (const float*)d_in[21];
  const float* Ws2  = (const float*)d_in[22];
  const float* bs2  = (const float*)d_in[23];
  float* out = (float*)d_out;

  // workspace layout (~59 MB)
  __half* qb  = (__half*)d_ws;                       // NN*128
  __half* kb  = qb + (size_t)NN * 128;               // NN*128
  u16*    vb  = (u16*)(kb + (size_t)NN * 128);       // NN*128 bf16
  __half* snb = (__half*)(vb + (size_t)NN * 128);    // NN*64
  __half* Ws1h = snb + (size_t)NN * 64;              // 8192
  float*  Ws2t = (float*)(Ws1h + 8192);              // 1024
  u16*    numb = (u16*)(Ws2t + 1024);                // NN*128 bf16
  float*  den  = (float*)(numb + (size_t)NN * 128);  // NN*8

  // zero num (bf16) + den (f32) in one contiguous memset
  hipMemsetAsync(numb, 0, (size_t)NN * 128 * 2 + (size_t)NN * 8 * 4, stream);

  prep_w<<<36, 256, 0, stream>>>(Ws1, Ws2, Ws1h, Ws2t);

  node_pre<<<(NN + NB - 1) / NB, 384, 0, stream>>>(
      x, seq, ln_g, ln_b, Wq, bq, Wk, bk, Wv, bv, qb, kb, vb, snb);

  edge_fused<<<EE / 256, 256, 0, stream>>>(
      ei, ea, qb, kb, vb, snb,
      We0a, be0a, We0b, be0b, We1a, be1a, We1b, be1b,
      Ws1h, bs1, Ws2t, bs2, den, numb);

  finalize_k<<<(NN * 16) / 256, 256, 0, stream>>>(x, numb, den, out);
}

// Round 4
// 728.205 us; speedup vs baseline: 1.9960x; 1.0550x over previous
//
#include <hip/hip_runtime.h>
#include <hip/hip_fp16.h>

#define NN 50000
#define EE 800000

typedef unsigned int u32;
typedef unsigned short u16;

// ---------- helpers ----------
__device__ __forceinline__ float bf_lo(u32 u){ return __uint_as_float(u << 16); }
__device__ __forceinline__ float bf_hi(u32 u){ return __uint_as_float(u & 0xffff0000u); }
__device__ __forceinline__ u16 f2bf(float f){
  u32 x = __float_as_uint(f);
  x += 0x7fffu + ((x >> 16) & 1u);       // RNE
  return (u16)(x >> 16);
}
__device__ __forceinline__ float gelu_exact(float x){
  return x * 0.5f * (1.0f + erff(x * 0.70710678118654752f));
}
__device__ __forceinline__ float rcp_fast(float x){ return __builtin_amdgcn_rcpf(x); }
__device__ __forceinline__ float gelu_fast(float x){
  float x2 = x * x;
  float y  = x * fmaf(x2, 0.0356774081f, 0.7978845608f);
  float e  = __expf(y + y);
  return x - x * rcp_fast(e + 1.0f);
}
__device__ __forceinline__ float tanh_fast(float x){
  float e = __expf(x + x);
  return 1.0f - 2.0f * rcp_fast(e + 1.0f);
}
__device__ __forceinline__ void atomic_add_f32(float* p, float v){
  __hip_atomic_fetch_add(p, v, __ATOMIC_RELAXED, __HIP_MEMORY_SCOPE_AGENT);
}
__device__ __forceinline__ __half2 as_h2(u32 u){ return __builtin_bit_cast(__half2, u); }
__device__ __forceinline__ u32 pack2f(float a, float b){
  __half2 h = __floats2half2_rn(a, b);
  return __builtin_bit_cast(u32, h);
}
__device__ __forceinline__ float h2_lo(__half2 h){ return __half2float(__low2half(h)); }
__device__ __forceinline__ float h2_hi(__half2 h){ return __half2float(__high2half(h)); }

// ---------- kernel 1: LN + QKV (q,k f16; v bf16) + seq-normalize (f16) ----------
#define NB 48
__global__ __launch_bounds__(384) void node_pre(
    const float* __restrict__ x, const float* __restrict__ seq,
    const float* __restrict__ ln_g, const float* __restrict__ ln_b,
    const float* __restrict__ Wq, const float* __restrict__ bq,
    const float* __restrict__ Wk, const float* __restrict__ bk,
    const float* __restrict__ Wv, const float* __restrict__ bv,
    __half* __restrict__ qb, __half* __restrict__ kb,
    u16* __restrict__ vb, __half* __restrict__ snb)
{
  __shared__ float h_lds[NB][132];
  const int t = threadIdx.x;
  const int nbase = blockIdx.x * NB;

  {
    const int row = t >> 3, sub = t & 7;
    const int n = nbase + row;
    if (n < NN) {
      const float* xp = x + (size_t)n * 128 + sub * 16;
      float vals[16];
      float s = 0.f, ss = 0.f;
      #pragma unroll
      for (int j = 0; j < 16; j += 4) {
        float4 v4 = *(const float4*)(xp + j);
        vals[j] = v4.x; vals[j+1] = v4.y; vals[j+2] = v4.z; vals[j+3] = v4.w;
        s += v4.x + v4.y + v4.z + v4.w;
        ss += v4.x*v4.x + v4.y*v4.y + v4.z*v4.z + v4.w*v4.w;
      }
      #pragma unroll
      for (int o = 1; o < 8; o <<= 1) { s += __shfl_xor(s, o); ss += __shfl_xor(ss, o); }
      float mu = s * (1.f / 128.f);
      float var = ss * (1.f / 128.f) - mu * mu;
      float rs = rsqrtf(var + 1e-5f);
      #pragma unroll
      for (int j = 0; j < 16; j++) {
        int c = sub * 16 + j;
        h_lds[row][c] = (vals[j] - mu) * rs * ln_g[c] + ln_b[c];
      }
      const float* sp = seq + (size_t)n * 64 + sub * 8;
      float4 a = *(const float4*)(sp);
      float4 b4 = *(const float4*)(sp + 4);
      float q2 = a.x*a.x + a.y*a.y + a.z*a.z + a.w*a.w
               + b4.x*b4.x + b4.y*b4.y + b4.z*b4.z + b4.w*b4.w;
      #pragma unroll
      for (int o = 1; o < 8; o <<= 1) q2 += __shfl_xor(q2, o);
      float inv = 1.0f / fmaxf(sqrtf(q2), 1e-12f);
      __half* op = snb + (size_t)n * 64 + sub * 8;
      op[0]=__float2half(a.x*inv);  op[1]=__float2half(a.y*inv);
      op[2]=__float2half(a.z*inv);  op[3]=__float2half(a.w*inv);
      op[4]=__float2half(b4.x*inv); op[5]=__float2half(b4.y*inv);
      op[6]=__float2half(b4.z*inv); op[7]=__float2half(b4.w*inv);
    }
  }
  __syncthreads();

  const int mat = t >> 7;
  const int r = t & 127;
  const float* W = (mat == 0) ? Wq : (mat == 1) ? Wk : Wv;
  const float* B = (mat == 0) ? bq : (mat == 1) ? bk : bv;

  float acc[NB];
  #pragma unroll
  for (int n = 0; n < NB; n++) acc[n] = 0.f;

  for (int i = 0; i < 128; i += 4) {
    float4 w4 = *(const float4*)(W + (size_t)r * 128 + i);
    #pragma unroll
    for (int n = 0; n < NB; n++) {
      float4 h4 = *(const float4*)(&h_lds[n][i]);
      acc[n] += w4.x*h4.x + w4.y*h4.y + w4.z*h4.z + w4.w*h4.w;
    }
  }
  float bias = B[r];
  __half* Oh = (mat == 0) ? qb : kb;
  #pragma unroll
  for (int n = 0; n < NB; n++) {
    int ng = nbase + n;
    if (ng < NN) {
      float val = acc[n] + bias;
      if (mat == 2) vb[(size_t)ng * 128 + r] = f2bf(val);
      else          Oh[(size_t)ng * 128 + r] = __float2half(val);
    }
  }
}

// ---------- kernel 2: fused edge logits + softmax-numerator scatter ----------
__global__ __launch_bounds__(256, 4) void edge_fused(
    const int* __restrict__ ei, const float* __restrict__ edge_attr,
    const __half* __restrict__ qb, const __half* __restrict__ kb,
    const u16* __restrict__ vb, const __half* __restrict__ snb,
    const float* __restrict__ We0a, const float* __restrict__ be0a,
    const float* __restrict__ We0b, const float* __restrict__ be0b,
    const float* __restrict__ We1a, const float* __restrict__ be1a,
    const float* __restrict__ We1b, const float* __restrict__ be1b,
    const float* __restrict__ Ws1, const float* __restrict__ bs1,
    const float* __restrict__ Ws2, const float* __restrict__ bs2,
    float* __restrict__ den, u16* __restrict__ numb)
{
  __shared__ u32   sW1[128 * 32];      // 16 KB: Ws1 f16 pairs [j][ipair]
  __shared__ u32   sW2[128 * 4];       // 2 KB : Ws2^T f16 pairs [j][opair]
  __shared__ float sbs1[128];
  __shared__ u32   sWeah[2 * 264];     // f16 pairs [sel][j*8+q], stride-padded
  __shared__ u32   sWebTh[2 * 136];    // f16 pairs [sel][j*4+q], stride-padded
  __shared__ float sbea[64];
  __shared__ float sbeb[16];
  __shared__ u32   sExPk[256 * 4];     // 4 KB: bf16-packed ex per edge
  __shared__ u32   sSrcOff[256], sDstOff[256];

  const int t = threadIdx.x;
  // --- weight staging (f32 -> packed f16) ---
  for (int idx = t; idx < 4096; idx += 256) {
    int j = idx >> 5, ip = idx & 31;
    sW1[idx] = pack2f(Ws1[j * 64 + 2 * ip], Ws1[j * 64 + 2 * ip + 1]);
  }
  for (int idx = t; idx < 512; idx += 256) {
    int j = idx >> 2, q = idx & 3;
    sW2[idx] = pack2f(Ws2[(2 * q) * 128 + j], Ws2[(2 * q + 1) * 128 + j]);
  }
  if (t < 128) sbs1[t] = bs1[t];
  for (int idx = t; idx < 512; idx += 256) {
    int e2 = idx >> 8, rem = idx & 255, j = rem >> 3, q = rem & 7;
    const float* W = e2 ? We1a : We0a;
    sWeah[e2 * 264 + rem] = pack2f(W[j * 16 + 2 * q], W[j * 16 + 2 * q + 1]);
  }
  {
    int idx = t;
    if (idx < 256) {
      int e2 = idx >> 7, rem = idx & 127, j = rem >> 2, q = rem & 3;
      const float* W = e2 ? We1b : We0b;
      sWebTh[e2 * 136 + rem] = pack2f(W[(2 * q) * 32 + j], W[(2 * q + 1) * 32 + j]);
    }
  }
  if (t < 64) sbea[t] = (t < 32) ? be0a[t] : be1a[t - 32];
  if (t < 16) sbeb[t] = (t < 8) ? be0b[t] : be1b[t - 8];
  __syncthreads();

  const int e = blockIdx.x * 256 + t;
  const int lane = t & 63, wid = t >> 6;
  const int src = ei[e];
  const int dst = ei[EE + e];

  sSrcOff[t] = (u32)src * 256u;   // vb row = 128 bf16 = 256 B
  sDstOff[t] = (u32)dst * 256u;   // numb row = 256 B

  // ---- edge-type MLP (packed f16) ----
  __half2 ef2[8]; float a16, a17;
  {
    const float2* p2 = (const float2*)(edge_attr + (size_t)e * 18);
    float2 p[9];
    #pragma unroll
    for (int i = 0; i < 9; i++) p[i] = p2[i];
    #pragma unroll
    for (int i = 0; i < 8; i++) ef2[i] = __floats2half2_rn(p[i].x, p[i].y);
    a16 = p[8].x; a17 = p[8].y;
  }
  const int sel = (a17 > a16) ? 1 : 0;
  const u32* Wah = sWeah + sel * 264;
  const u32* Wbh = sWebTh + sel * 136;
  const float* ba = sbea + sel * 32;
  const float* bb = sbeb + sel * 8;

  __half2 m2[4];
  #pragma unroll
  for (int q = 0; q < 4; q++) m2[q] = __floats2half2_rn(bb[2 * q], bb[2 * q + 1]);
  for (int j = 0; j < 32; j++) {
    __half2 a = __floats2half2_rn(0.f, 0.f);
    #pragma unroll
    for (int q = 0; q < 8; q++) a = __hfma2(as_h2(Wah[j * 8 + q]), ef2[q], a);
    float hs = h2_lo(a) + h2_hi(a) + ba[j];
    hs = fmaxf(hs, 0.f);
    __half2 hs2 = __float2half2_rn(hs);
    #pragma unroll
    for (int q = 0; q < 4; q++) m2[q] = __hfma2(as_h2(Wbh[j * 4 + q]), hs2, m2[q]);
  }
  float m[8];
  #pragma unroll
  for (int q = 0; q < 4; q++) { m[2*q] = h2_lo(m2[q]); m[2*q+1] = h2_hi(m2[q]); }

  // ---- sd = sn[dst]-sn[src] (packed f16) ----
  __half2 sd2[32];
  {
    const uint4* sA = (const uint4*)(snb + (size_t)dst * 64);
    const uint4* sB = (const uint4*)(snb + (size_t)src * 64);
    #pragma unroll
    for (int u = 0; u < 8; u++) {
      uint4 ua = sA[u], ub = sB[u];
      sd2[u*4+0] = __hsub2(as_h2(ua.x), as_h2(ub.x));
      sd2[u*4+1] = __hsub2(as_h2(ua.y), as_h2(ub.y));
      sd2[u*4+2] = __hsub2(as_h2(ua.z), as_h2(ub.z));
      sd2[u*4+3] = __hsub2(as_h2(ua.w), as_h2(ub.w));
    }
  }

  // ---- seq MLP: LDS broadcast weights, packed f16 FMA ----
  __half2 sb2[4];
  #pragma unroll
  for (int q = 0; q < 4; q++) sb2[q] = __floats2half2_rn(bs2[2 * q], bs2[2 * q + 1]);
  for (int j = 0; j < 128; j++) {
    const u32* wp = sW1 + j * 32;
    __half2 a0 = __floats2half2_rn(0.f, 0.f), a1 = a0, a2 = a0, a3 = a0;
    #pragma unroll
    for (int u = 0; u < 32; u += 4) {
      a0 = __hfma2(as_h2(wp[u + 0]), sd2[u + 0], a0);
      a1 = __hfma2(as_h2(wp[u + 1]), sd2[u + 1], a1);
      a2 = __hfma2(as_h2(wp[u + 2]), sd2[u + 2], a2);
      a3 = __hfma2(as_h2(wp[u + 3]), sd2[u + 3], a3);
    }
    __half2 s = __hadd2(__hadd2(a0, a1), __hadd2(a2, a3));
    float accf = h2_lo(s) + h2_hi(s) + sbs1[j];
    float g = gelu_fast(accf);
    __half2 g2 = __float2half2_rn(g);
    const u32* w2p = sW2 + j * 4;
    #pragma unroll
    for (int q = 0; q < 4; q++) sb2[q] = __hfma2(as_h2(w2p[q]), g2, sb2[q]);
  }
  float tv[8];
  #pragma unroll
  for (int q = 0; q < 4; q++) {
    tv[2*q]   = tanh_fast(h2_lo(sb2[q]));
    tv[2*q+1] = tanh_fast(h2_hi(sb2[q]));
  }

  // ---- QK dots (f16) + exp + den atomics + packed ex to LDS ----
  {
    const uint4* qp4 = (const uint4*)(qb + (size_t)dst * 128);
    const uint4* kp4 = (const uint4*)(kb + (size_t)src * 128);
    float ex[8];
    #pragma unroll
    for (int h = 0; h < 8; h++) {
      uint4 qa = qp4[2*h], qc = qp4[2*h+1];
      uint4 ka = kp4[2*h], kc = kp4[2*h+1];
      __half2 d2 = __floats2half2_rn(0.f, 0.f);
      d2 = __hfma2(as_h2(qa.x), as_h2(ka.x), d2);
      d2 = __hfma2(as_h2(qa.y), as_h2(ka.y), d2);
      d2 = __hfma2(as_h2(qa.z), as_h2(ka.z), d2);
      d2 = __hfma2(as_h2(qa.w), as_h2(ka.w), d2);
      d2 = __hfma2(as_h2(qc.x), as_h2(kc.x), d2);
      d2 = __hfma2(as_h2(qc.y), as_h2(kc.y), d2);
      d2 = __hfma2(as_h2(qc.z), as_h2(kc.z), d2);
      d2 = __hfma2(as_h2(qc.w), as_h2(kc.w), d2);
      float dot = h2_lo(d2) + h2_hi(d2);
      float logit = dot * 0.25f + m[h] + 0.1f * tv[h];
      ex[h] = __expf(logit);
      atomic_add_f32(&den[(size_t)dst * 8 + h], ex[h]);
    }
    u32 pk0, pk1, pk2, pk3;
    asm("v_cvt_pk_bf16_f32 %0, %1, %2" : "=v"(pk0) : "v"(ex[0]), "v"(ex[1]));
    asm("v_cvt_pk_bf16_f32 %0, %1, %2" : "=v"(pk1) : "v"(ex[2]), "v"(ex[3]));
    asm("v_cvt_pk_bf16_f32 %0, %1, %2" : "=v"(pk2) : "v"(ex[4]), "v"(ex[5]));
    asm("v_cvt_pk_bf16_f32 %0, %1, %2" : "=v"(pk3) : "v"(ex[6]), "v"(ex[7]));
    uint4 st; st.x = pk0; st.y = pk1; st.z = pk2; st.w = pk3;
    *(uint4*)(sExPk + t * 4) = st;
  }

  // ---- scatter: unroll-8 batches, deep-pipelined loads + atomics ----
  {
    const int h   = lane >> 3;
    const int hw  = h >> 1;
    const int hsh = (h & 1) << 4;
    const char* vbase = (const char*)vb + (size_t)(lane * 4);
    char* nbase = (char*)numb + (size_t)(lane * 4);
    const int wb = wid * 64;
    #pragma unroll 1
    for (int el0 = 0; el0 < 64; el0 += 8) {
      u32 so[8], dof[8]; float exb[8];
      #pragma unroll
      for (int q = 0; q < 8; q++) {
        so[q]  = sSrcOff[wb + el0 + q];
        dof[q] = sDstOff[wb + el0 + q];
        u32 pkv = sExPk[(wb + el0 + q) * 4 + hw];
        exb[q] = __uint_as_float(((pkv >> hsh) & 0xffffu) << 16);
      }
      u32 vv[8];
      #pragma unroll
      for (int q = 0; q < 8; q++) vv[q] = *(const u32*)(vbase + so[q]);
      #pragma unroll
      for (int q = 0; q < 8; q++) {
        float p0 = bf_lo(vv[q]) * exb[q];
        float p1 = bf_hi(vv[q]) * exb[q];
        u32 pk_;
        asm("v_cvt_pk_bf16_f32 %0, %1, %2" : "=v"(pk_) : "v"(p0), "v"(p1));
        asm volatile("global_atomic_pk_add_bf16 %0, %1, off"
                     :: "v"((void*)(nbase + (size_t)dof[q])), "v"(pk_));
      }
    }
  }
}

// ---------- kernel 3: out = gelu(num/(den+1e-12)) + x ----------
__global__ __launch_bounds__(256) void finalize_k(
    const float* __restrict__ x, const u16* __restrict__ numb,
    const float* __restrict__ den, float* __restrict__ out)
{
  int idx = blockIdx.x * 256 + threadIdx.x;   // NN*16 units of 8 channels
  int n = idx >> 4;
  int part = idx & 15;
  int c0 = part * 8;
  int h = part >> 1;
  float inv = 1.0f / (den[(size_t)n * 8 + h] + 1e-12f);
  uint4 nv = *(const uint4*)(numb + (size_t)n * 128 + c0);
  float4 xa = *(const float4*)(x + (size_t)n * 128 + c0);
  float4 xb = *(const float4*)(x + (size_t)n * 128 + c0 + 4);
  float4 oa, ob;
  oa.x = gelu_exact(bf_lo(nv.x) * inv) + xa.x;
  oa.y = gelu_exact(bf_hi(nv.x) * inv) + xa.y;
  oa.z = gelu_exact(bf_lo(nv.y) * inv) + xa.z;
  oa.w = gelu_exact(bf_hi(nv.y) * inv) + xa.w;
  ob.x = gelu_exact(bf_lo(nv.z) * inv) + xb.x;
  ob.y = gelu_exact(bf_hi(nv.z) * inv) + xb.y;
  ob.z = gelu_exact(bf_lo(nv.w) * inv) + xb.z;
  ob.w = gelu_exact(bf_hi(nv.w) * inv) + xb.w;
  *(float4*)(out + (size_t)n * 128 + c0) = oa;
  *(float4*)(out + (size_t)n * 128 + c0 + 4) = ob;
}

extern "C" void kernel_launch(void* const* d_in, const int* in_sizes, int n_in,
                              void* d_out, int out_size, void* d_ws, size_t ws_size,
                              hipStream_t stream)
{
  const float* x    = (const float*)d_in[0];
  const int*   ei   = (const int*)d_in[1];
  const float* ea   = (const float*)d_in[2];
  const float* seq  = (const float*)d_in[3];
  const float* ln_g = (const float*)d_in[4];
  const float* ln_b = (const float*)d_in[5];
  const float* Wq   = (const float*)d_in[6];
  const float* bq   = (const float*)d_in[7];
  const float* Wk   = (const float*)d_in[8];
  const float* bk   = (const float*)d_in[9];
  const float* Wv   = (const float*)d_in[10];
  const float* bv   = (const float*)d_in[11];
  const float* We0a = (const float*)d_in[12];
  const float* be0a = (const float*)d_in[13];
  const float* We0b = (const float*)d_in[14];
  const float* be0b = (const float*)d_in[15];
  const float* We1a = (const float*)d_in[16];
  const float* be1a = (const float*)d_in[17];
  const float* We1b = (const float*)d_in[18];
  const float* be1b = (const float*)d_in[19];
  const float* Ws1  = (const float*)d_in[20];
  const float* bs1  = (const float*)d_in[21];
  const float* Ws2  = (const float*)d_in[22];
  const float* bs2  = (const float*)d_in[23];
  float* out = (float*)d_out;

  // workspace layout
  __half* qb  = (__half*)d_ws;                       // NN*128 f16
  __half* kb  = qb + (size_t)NN * 128;               // NN*128 f16
  u16*    vb  = (u16*)(kb + (size_t)NN * 128);       // NN*128 bf16
  __half* snb = (__half*)(vb + (size_t)NN * 128);    // NN*64 f16
  u16*    numb = (u16*)(snb + (size_t)NN * 64);      // NN*128 bf16
  float*  den  = (float*)(numb + (size_t)NN * 128);  // NN*8 f32

  hipMemsetAsync(numb, 0, (size_t)NN * 128 * 2 + (size_t)NN * 8 * 4, stream);

  node_pre<<<(NN + NB - 1) / NB, 384, 0, stream>>>(
      x, seq, ln_g, ln_b, Wq, bq, Wk, bk, Wv, bv, qb, kb, vb, snb);

  edge_fused<<<EE / 256, 256, 0, stream>>>(
      ei, ea, qb, kb, vb, snb,
      We0a, be0a, We0b, be0b, We1a, be1a, We1b, be1b,
      Ws1, bs1, Ws2, bs2, den, numb);

  finalize_k<<<(NN * 16) / 256, 256, 0, stream>>>(x, numb, den, out);
}